// Round 1
// baseline (256.472 us; speedup 1.0000x reference)
//
#include <hip/hip_runtime.h>
#include <stdint.h>

#define D_DIM 1024
#define INV_T 14.2857142857142857f

typedef __attribute__((ext_vector_type(8))) __bf16 bf16x8;
typedef __attribute__((ext_vector_type(4))) float f32x4;

static __device__ __forceinline__ unsigned short f2bf(float x) {
  union { float f; unsigned int u; } v; v.f = x;
  unsigned int r = v.u + 0x7FFFu + ((v.u >> 16) & 1u);
  return (unsigned short)(r >> 16);
}

// ---------------- Kernel 1: L2-normalize rows (fp32 -> bf16) + diagonal dot ----------------
__global__ __launch_bounds__(256) void norm_diag_kernel(
    const float* __restrict__ A, const float* __restrict__ T,
    unsigned short* __restrict__ An, unsigned short* __restrict__ Tn,
    float* __restrict__ diag)
{
  const int row = blockIdx.x;
  const int tid = threadIdx.x;              // 256 threads, each owns 4 elems (D=1024)
  const size_t base = (size_t)row * D_DIM;
  const float4 av = ((const float4*)(A + base))[tid];
  const float4 tv = ((const float4*)(T + base))[tid];
  float sa = av.x*av.x + av.y*av.y + av.z*av.z + av.w*av.w;
  float st = tv.x*tv.x + tv.y*tv.y + tv.z*tv.z + tv.w*tv.w;
  float sd = av.x*tv.x + av.y*tv.y + av.z*tv.z + av.w*tv.w;
  #pragma unroll
  for (int m = 1; m < 64; m <<= 1) {
    sa += __shfl_xor(sa, m, 64);
    st += __shfl_xor(st, m, 64);
    sd += __shfl_xor(sd, m, 64);
  }
  __shared__ float red[3][4];
  const int wid = tid >> 6;
  if ((tid & 63) == 0) { red[0][wid] = sa; red[1][wid] = st; red[2][wid] = sd; }
  __syncthreads();
  sa = red[0][0] + red[0][1] + red[0][2] + red[0][3];
  st = red[1][0] + red[1][1] + red[1][2] + red[1][3];
  sd = red[2][0] + red[2][1] + red[2][2] + red[2][3];
  const float ra = rsqrtf(sa), rt = rsqrtf(st);
  if (tid == 0) diag[row] = sd * ra * rt * INV_T;
  ushort4 ao, to;
  ao.x = f2bf(av.x * ra); ao.y = f2bf(av.y * ra); ao.z = f2bf(av.z * ra); ao.w = f2bf(av.w * ra);
  to.x = f2bf(tv.x * rt); to.y = f2bf(tv.y * rt); to.z = f2bf(tv.z * rt); to.w = f2bf(tv.w * rt);
  ((ushort4*)(An + base))[tid] = ao;
  ((ushort4*)(Tn + base))[tid] = to;
}

// ---------------- Kernel 2: fused bf16 GEMM (A . T^T / temp) + exp + row/col sum-exp ----------------
__device__ __forceinline__ void gload_lds16(const void* g, void* l) {
  __builtin_amdgcn_global_load_lds(
      (const __attribute__((address_space(1))) unsigned int*)g,
      (__attribute__((address_space(3))) unsigned int*)l, 16, 0, 0);
}

__global__ __launch_bounds__(256, 2) void gemm_lse_kernel(
    const unsigned short* __restrict__ An, const unsigned short* __restrict__ Tn,
    float* __restrict__ Srow, float* __restrict__ Scol, int nbc)
{
  __shared__ unsigned short As[128 * 64];   // [row 0..127][k 0..63], linear (global_load_lds needs linear dest)
  __shared__ unsigned short Bs[128 * 64];

  // XCD-aware bijective swizzle (gridDim.x % 8 == 0)
  const int nwg = gridDim.x;
  const int bid = blockIdx.x;
  const int cpx = nwg >> 3;
  const int swz = (bid & 7) * cpx + (bid >> 3);
  const int brow = swz / nbc;
  const int bcol = swz - brow * nbc;

  const int tid  = threadIdx.x;
  const int lane = tid & 63;
  const int wid  = tid >> 6;        // 4 waves, 2x2 wave grid; each wave owns 64x64 output
  const int wr   = wid >> 1, wc = wid & 1;
  const int lcol = lane & 15, lrow = lane >> 4;

  const unsigned short* aP = An + (size_t)brow * 128 * D_DIM;
  const unsigned short* bP = Tn + (size_t)bcol * 128 * D_DIM;

  f32x4 acc[4][4] = {};

  for (int k0 = 0; k0 < D_DIM; k0 += 64) {
    // stage 128x64 bf16 per operand: 1024 chunks of 16B, 4 issues per thread per operand
    #pragma unroll
    for (int it = 0; it < 4; ++it) {
      const int c  = it * 256 + tid;     // chunk index 0..1023
      const int r  = c >> 3;             // tile row
      const int c8 = (c & 7) * 8;        // k-offset within tile row
      gload_lds16(aP + (size_t)r * D_DIM + k0 + c8, &As[c * 8]);
      gload_lds16(bP + (size_t)r * D_DIM + k0 + c8, &Bs[c * 8]);
    }
    __syncthreads();                     // drains vmcnt before barrier
    #pragma unroll
    for (int kk = 0; kk < 64; kk += 32) {
      const int ko = kk + lrow * 8;      // lane holds 8 contiguous k
      bf16x8 af[4], bfr[4];
      #pragma unroll
      for (int m = 0; m < 4; ++m)
        af[m] = *(const bf16x8*)&As[(wr * 64 + m * 16 + lcol) * 64 + ko];
      #pragma unroll
      for (int n = 0; n < 4; ++n)
        bfr[n] = *(const bf16x8*)&Bs[(wc * 64 + n * 16 + lcol) * 64 + ko];
      #pragma unroll
      for (int m = 0; m < 4; ++m)
        #pragma unroll
        for (int n = 0; n < 4; ++n)
          acc[m][n] = __builtin_amdgcn_mfma_f32_16x16x32_bf16(af[m], bfr[n], acc[m][n], 0, 0, 0);
    }
    __syncthreads();
  }

  // Epilogue: e = exp(sim/T); accumulate per-row and per-col sums.
  // C/D mapping (m89/m91 verified): col = lane&15, row = (lane>>4)*4 + reg
  float rowsum[4][4];                    // [m][reg]
  float colsum[4];                       // [n]
  #pragma unroll
  for (int m = 0; m < 4; ++m)
    #pragma unroll
    for (int r = 0; r < 4; ++r) rowsum[m][r] = 0.f;
  #pragma unroll
  for (int n = 0; n < 4; ++n) {
    float cs = 0.f;
    #pragma unroll
    for (int m = 0; m < 4; ++m)
      #pragma unroll
      for (int r = 0; r < 4; ++r) {
        const float e = __expf(acc[m][n][r] * INV_T);
        rowsum[m][r] += e;
        cs += e;
      }
    colsum[n] = cs;
  }
  // Row sums: reduce across the 16 lanes (lane bits 0-3) holding the row's columns
  #pragma unroll
  for (int m = 0; m < 4; ++m)
    #pragma unroll
    for (int r = 0; r < 4; ++r) {
      float v = rowsum[m][r];
      v += __shfl_xor(v, 1, 64);
      v += __shfl_xor(v, 2, 64);
      v += __shfl_xor(v, 4, 64);
      v += __shfl_xor(v, 8, 64);
      if (lcol == 0)
        atomicAdd(&Srow[brow * 128 + wr * 64 + m * 16 + lrow * 4 + r], v);
    }
  // Col sums: reduce across lane bits 4-5 (the 4 row-groups)
  #pragma unroll
  for (int n = 0; n < 4; ++n) {
    float v = colsum[n];
    v += __shfl_xor(v, 16, 64);
    v += __shfl_xor(v, 32, 64);
    if (lane < 16)
      atomicAdd(&Scol[bcol * 128 + wc * 64 + n * 16 + lcol], v);
  }
}

// ---------------- Kernel 3: loss = mean(0.5*(log Srow + log Scol) - diag) ----------------
__global__ __launch_bounds__(256) void loss_kernel(
    const float* __restrict__ Srow, const float* __restrict__ Scol,
    const float* __restrict__ diag, float* __restrict__ out, int B)
{
  float s = 0.f;
  for (int i = threadIdx.x; i < B; i += 256)
    s += 0.5f * (__logf(Srow[i]) + __logf(Scol[i])) - diag[i];
  #pragma unroll
  for (int m = 1; m < 64; m <<= 1) s += __shfl_xor(s, m, 64);
  __shared__ float red[4];
  if ((threadIdx.x & 63) == 0) red[threadIdx.x >> 6] = s;
  __syncthreads();
  if (threadIdx.x == 0) out[0] = (red[0] + red[1] + red[2] + red[3]) / (float)B;
}

extern "C" void kernel_launch(void* const* d_in, const int* in_sizes, int n_in,
                              void* d_out, int out_size, void* d_ws, size_t ws_size,
                              hipStream_t stream) {
  const float* A = (const float*)d_in[0];
  const float* T = (const float*)d_in[1];
  const int B = in_sizes[0] / D_DIM;     // 8192
  const int nbc = B / 128;               // 64

  char* ws = (char*)d_ws;
  unsigned short* An = (unsigned short*)ws;                          // B*D bf16 = 16 MB
  unsigned short* Tn = (unsigned short*)(ws + (size_t)B * D_DIM * 2); // 16 MB
  float* Srow = (float*)(ws + (size_t)B * D_DIM * 4);                // B floats
  float* Scol = Srow + B;
  float* diag = Scol + B;

  hipMemsetAsync(Srow, 0, (size_t)2 * B * sizeof(float), stream);
  norm_diag_kernel<<<B, 256, 0, stream>>>(A, T, An, Tn, diag);
  gemm_lse_kernel<<<nbc * nbc, 256, 0, stream>>>(An, Tn, Srow, Scol, nbc);
  loss_kernel<<<1, 256, 0, stream>>>(Srow, Scol, diag, (float*)d_out, B);
}